// Round 1
// baseline (169.096 us; speedup 1.0000x reference)
//
#include <hip/hip_runtime.h>
#include <math.h>

// Problem constants
//   B=4, L=4096, D_MODEL=1024, N_HEADS=16, D_HEAD=64, MODES=32
// Rank-64 reassociation:
//   A  = F @ q          [4][64][1024]  (F: 64x4096 DFT rows, bf16 MFMA, atomic K-split)
//   C  = A @ Wv^T       (+ mode-0 bias: C[0] += 4096*bv, since sum_t cos(2pi k t/L)=0 for k!=0)
//   Y  = C * (wr + i wi) interleaved re/im rows
//   Z  = Y @ Wo^T
//   out= G @ Z + bo     (G: 4096x64 inverse-DFT cols with 1/L,2/L folded; col j=1 zeroed
//                        because pocketfft irfft ignores Im of the DC bin)

typedef __attribute__((ext_vector_type(8))) short bf16x8;
typedef __attribute__((ext_vector_type(8))) unsigned short ushort8;
typedef __attribute__((ext_vector_type(4))) float f32x4;

__device__ __forceinline__ unsigned short f2bf(float x) {
    union { float f; unsigned int u; } c; c.f = x;
    unsigned int u = c.u + 0x7FFFu + ((c.u >> 16) & 1u);   // RNE
    return (unsigned short)(u >> 16);
}

// ---------------------------------------------------------------------------
// init: F[64][4096] bf16, G[4096][64] bf16, zero A (262144 floats)
// ---------------------------------------------------------------------------
__global__ __launch_bounds__(256) void k_init(unsigned short* __restrict__ F,
                                              unsigned short* __restrict__ G,
                                              float* __restrict__ A) {
    int idx = blockIdx.x * 256 + threadIdx.x;        // 0..262143
    const float w0 = 1.5339807878856412e-3f;          // 2*pi/4096
    {   // F[j][t]: j=2k -> cos(2pi k t/L), j=2k+1 -> -sin(2pi k t/L)
        int j = idx >> 12, t = idx & 4095, k = j >> 1;
        int r = (k * t) & 4095;
        float s, c; sincosf((float)r * w0, &s, &c);
        F[idx] = f2bf((j & 1) ? -s : c);
    }
    {   // G[t][j]: j=2k -> ck*cos, j=2k+1 -> -ck*sin (0 for k==0), ck = (k?2:1)/L
        int j = idx & 63, k = j >> 1;
        int t = idx >> 6;
        int r = (k * t) & 4095;
        float s, c; sincosf((float)r * w0, &s, &c);
        float ck = (k == 0) ? (1.0f / 4096.0f) : (2.0f / 4096.0f);
        float v = (j & 1) ? ((k == 0) ? 0.0f : -ck * s) : ck * c;
        G[idx] = f2bf(v);
    }
    A[idx] = 0.0f;
}

// ---------------------------------------------------------------------------
// K1: A[b][64 j][1024 n] += F[64 j][t-chunk] @ q[b][t-chunk][32 n]
// grid = b(4) x ntile(32) x kp(16), 1 wave per block, fp32 atomicAdd epilogue
// ---------------------------------------------------------------------------
__global__ __launch_bounds__(64) void k_dft_fwd(const float* __restrict__ q,
                                                const unsigned short* __restrict__ F,
                                                float* __restrict__ A) {
    __shared__ __align__(16) unsigned short Ft[64 * 40];  // [j][t] pad->40
    __shared__ __align__(16) unsigned short qT[32 * 40];  // [n][t] pad->40
    int blk = blockIdx.x;
    int kp = blk & 15, nt = (blk >> 4) & 31, b = blk >> 9;
    int n0 = nt * 32, t0 = kp * 256;
    int lane = threadIdx.x;
    int lm = lane & 15, q4 = lane >> 4;
    int nn4 = (lane & 7) * 4, th = lane >> 3;
    f32x4 acc[4][2] = {};
    for (int ks = 0; ks < 8; ++ks) {
        int tb = t0 + ks * 32;
        // stage F tile [64][32] (L2-resident, row per lane)
        #pragma unroll
        for (int i = 0; i < 4; ++i) {
            ushort8 v = *(const ushort8*)&F[lane * 4096 + tb + i * 8];
            *(ushort8*)&Ft[lane * 40 + i * 8] = v;
        }
        // stage q^T tile [32 n][32 t], coalesced float4 reads, bf16 transpose
        #pragma unroll
        for (int r2 = 0; r2 < 4; ++r2) {
            int tl = r2 * 8 + th;
            float4 v = *(const float4*)&q[(size_t)(b * 4096 + tb + tl) * 1024 + n0 + nn4];
            qT[(nn4 + 0) * 40 + tl] = f2bf(v.x);
            qT[(nn4 + 1) * 40 + tl] = f2bf(v.y);
            qT[(nn4 + 2) * 40 + tl] = f2bf(v.z);
            qT[(nn4 + 3) * 40 + tl] = f2bf(v.w);
        }
        __syncthreads();
        bf16x8 af[4], bq[2];
        #pragma unroll
        for (int mt = 0; mt < 4; ++mt)
            af[mt] = *(const bf16x8*)&Ft[(mt * 16 + lm) * 40 + q4 * 8];
        #pragma unroll
        for (int ntt = 0; ntt < 2; ++ntt)
            bq[ntt] = *(const bf16x8*)&qT[(ntt * 16 + lm) * 40 + q4 * 8];
        #pragma unroll
        for (int mt = 0; mt < 4; ++mt)
            #pragma unroll
            for (int ntt = 0; ntt < 2; ++ntt)
                acc[mt][ntt] = __builtin_amdgcn_mfma_f32_16x16x32_bf16(
                    af[mt], bq[ntt], acc[mt][ntt], 0, 0, 0);
        __syncthreads();
    }
    #pragma unroll
    for (int mt = 0; mt < 4; ++mt)
        #pragma unroll
        for (int ntt = 0; ntt < 2; ++ntt)
            #pragma unroll
            for (int r = 0; r < 4; ++r) {
                int j = mt * 16 + q4 * 4 + r;
                int n = n0 + ntt * 16 + lm;
                atomicAdd(&A[(b * 64 + j) * 1024 + n], acc[mt][ntt][r]);
            }
}

// ---------------------------------------------------------------------------
// K2/K4: P[kp][256 m][1024 n] = Ain[256 m][k-chunk] @ Bmat[1024 n][k-chunk]^T
// grid = mt(4) x nt(8) x kp(8); block 256 thr; Ain fp32 (template 0) or bf16 (1)
// ---------------------------------------------------------------------------
template<int ABF16>
__global__ __launch_bounds__(256) void k_gemm_bt(const void* __restrict__ Ain,
                                                 const float* __restrict__ Bmat,
                                                 float* __restrict__ P) {
    __shared__ __align__(16) unsigned short At[64 * 40];
    __shared__ __align__(16) unsigned short Wt[128 * 40];
    int blk = blockIdx.x;
    int kp = blk & 7, nt = (blk >> 3) & 7, mt = blk >> 6;
    int m0 = mt * 64, n0 = nt * 128, k0 = kp * 128;
    int tid = threadIdx.x, lane = tid & 63, w = tid >> 6;
    int lm = lane & 15, q4 = lane >> 4;
    int ma = tid >> 2, ka = (tid & 3) * 8;
    int nw = tid >> 1, kw = (tid & 1) * 16;
    f32x4 acc[4][2] = {};
    for (int ks = 0; ks < 4; ++ks) {
        int kb = k0 + ks * 32;
        if (ABF16) {
            ushort8 v = *(const ushort8*)&((const unsigned short*)Ain)[(m0 + ma) * 1024 + kb + ka];
            *(ushort8*)&At[ma * 40 + ka] = v;
        } else {
            const float* Af = (const float*)Ain;
            float4 x0 = *(const float4*)&Af[(m0 + ma) * 1024 + kb + ka];
            float4 x1 = *(const float4*)&Af[(m0 + ma) * 1024 + kb + ka + 4];
            ushort8 v;
            v[0]=f2bf(x0.x); v[1]=f2bf(x0.y); v[2]=f2bf(x0.z); v[3]=f2bf(x0.w);
            v[4]=f2bf(x1.x); v[5]=f2bf(x1.y); v[6]=f2bf(x1.z); v[7]=f2bf(x1.w);
            *(ushort8*)&At[ma * 40 + ka] = v;
        }
        {
            const float4* wp = (const float4*)&Bmat[(n0 + nw) * 1024 + kb + kw];
            float4 x0 = wp[0], x1 = wp[1], x2 = wp[2], x3 = wp[3];
            ushort8 v0, v1;
            v0[0]=f2bf(x0.x); v0[1]=f2bf(x0.y); v0[2]=f2bf(x0.z); v0[3]=f2bf(x0.w);
            v0[4]=f2bf(x1.x); v0[5]=f2bf(x1.y); v0[6]=f2bf(x1.z); v0[7]=f2bf(x1.w);
            v1[0]=f2bf(x2.x); v1[1]=f2bf(x2.y); v1[2]=f2bf(x2.z); v1[3]=f2bf(x2.w);
            v1[4]=f2bf(x3.x); v1[5]=f2bf(x3.y); v1[6]=f2bf(x3.z); v1[7]=f2bf(x3.w);
            *(ushort8*)&Wt[nw * 40 + kw]     = v0;
            *(ushort8*)&Wt[nw * 40 + kw + 8] = v1;
        }
        __syncthreads();
        bf16x8 af[4], bf[2];
        #pragma unroll
        for (int mti = 0; mti < 4; ++mti)
            af[mti] = *(const bf16x8*)&At[(mti * 16 + lm) * 40 + q4 * 8];
        #pragma unroll
        for (int ntt = 0; ntt < 2; ++ntt)
            bf[ntt] = *(const bf16x8*)&Wt[(w * 32 + ntt * 16 + lm) * 40 + q4 * 8];
        #pragma unroll
        for (int mti = 0; mti < 4; ++mti)
            #pragma unroll
            for (int ntt = 0; ntt < 2; ++ntt)
                acc[mti][ntt] = __builtin_amdgcn_mfma_f32_16x16x32_bf16(
                    af[mti], bf[ntt], acc[mti][ntt], 0, 0, 0);
        __syncthreads();
    }
    #pragma unroll
    for (int mti = 0; mti < 4; ++mti)
        #pragma unroll
        for (int ntt = 0; ntt < 2; ++ntt)
            #pragma unroll
            for (int r = 0; r < 4; ++r) {
                int m = m0 + mti * 16 + q4 * 4 + r;
                int n = n0 + w * 32 + ntt * 16 + lm;
                P[(size_t)kp * 262144 + m * 1024 + n] = acc[mti][ntt][r];
            }
}

// ---------------------------------------------------------------------------
// K3: reduce 8 partials + mode-0 bias + complex multiply by w -> Y bf16
// ---------------------------------------------------------------------------
__global__ __launch_bounds__(256) void k_cmul(const float* __restrict__ P,
                                              const float* __restrict__ bv,
                                              const float* __restrict__ wr,
                                              const float* __restrict__ wi,
                                              unsigned short* __restrict__ Y) {
    int idx = blockIdx.x * 256 + threadIdx.x;     // 131072 = 4*32*1024
    int n = idx & 1023, k = (idx >> 10) & 31, b = idx >> 15;
    int rowr = (b * 64 + 2 * k) * 1024 + n;
    int rowi = rowr + 1024;
    float re = 0.f, im = 0.f;
    #pragma unroll
    for (int p = 0; p < 8; ++p) {
        re += P[p * 262144 + rowr];
        im += P[p * 262144 + rowi];
    }
    if (k == 0) re += 4096.0f * bv[n];            // bias only feeds the DC bin
    int h = n >> 6, dh = n & 63;
    float a = wr[(h * 32 + k) * 64 + dh];
    float c = wi[(h * 32 + k) * 64 + dh];
    Y[rowr] = f2bf(re * a - im * c);
    Y[rowi] = f2bf(re * c + im * a);
}

// ---------------------------------------------------------------------------
// K4.5: reduce 8 partials -> Z bf16
// ---------------------------------------------------------------------------
__global__ __launch_bounds__(256) void k_reduce8(const float* __restrict__ P,
                                                 unsigned short* __restrict__ Z) {
    int idx = blockIdx.x * 256 + threadIdx.x;     // 262144
    float s = 0.f;
    #pragma unroll
    for (int p = 0; p < 8; ++p) s += P[p * 262144 + idx];
    Z[idx] = f2bf(s);
}

// ---------------------------------------------------------------------------
// K5: out[b][t][n] = G[t][64] @ Z[b][64][n] + bo[n]   (fp32 out, 64 MB write)
// grid = b(4) x ttile(32) x ntile(8); block 256 thr = 4 waves of 64x64
// ---------------------------------------------------------------------------
__global__ __launch_bounds__(256) void k_dft_inv(const unsigned short* __restrict__ G,
                                                 const unsigned short* __restrict__ Zb,
                                                 const float* __restrict__ bo,
                                                 float* __restrict__ out) {
    __shared__ __align__(16) unsigned short Gt[128 * 72];  // [t][j] pad->72
    __shared__ __align__(16) unsigned short ZT[128 * 72];  // [n][j] pad->72
    int blk = blockIdx.x;
    int nt = blk & 7, tt = (blk >> 3) & 31, b = blk >> 8;
    int n0 = nt * 128, t0 = tt * 128;
    int tid = threadIdx.x, lane = tid & 63, w = tid >> 6;
    int lm = lane & 15, q4 = lane >> 4;
    // stage G tile [128 t][64 j] (contiguous rows)
    {
        int ttl = tid >> 1, jj = (tid & 1) * 32;
        #pragma unroll
        for (int i = 0; i < 4; ++i) {
            ushort8 v = *(const ushort8*)&G[(t0 + ttl) * 64 + jj + i * 8];
            *(ushort8*)&Gt[ttl * 72 + jj + i * 8] = v;
        }
    }
    // stage Z^T tile [128 n][64 j]: read row pairs, pack (j,j+1) as u32 writes
    {
        int jp = tid & 31, hi = tid >> 5;      // jp: consecutive lanes -> distinct banks
        int j = jp * 2, nn0 = hi * 16;
        const unsigned short* r0 = &Zb[(b * 64 + j) * 1024 + n0 + nn0];
        const unsigned short* r1 = &Zb[(b * 64 + j + 1) * 1024 + n0 + nn0];
        ushort8 a0 = *(const ushort8*)r0, a1 = *(const ushort8*)(r0 + 8);
        ushort8 b0 = *(const ushort8*)r1, b1 = *(const ushort8*)(r1 + 8);
        #pragma unroll
        for (int i = 0; i < 8; ++i) {
            unsigned int v = (unsigned int)a0[i] | ((unsigned int)b0[i] << 16);
            *(unsigned int*)&ZT[(nn0 + i) * 72 + j] = v;
        }
        #pragma unroll
        for (int i = 0; i < 8; ++i) {
            unsigned int v = (unsigned int)a1[i] | ((unsigned int)b1[i] << 16);
            *(unsigned int*)&ZT[(nn0 + 8 + i) * 72 + j] = v;
        }
    }
    __syncthreads();
    int wt0 = (w >> 1) * 64, wn0 = (w & 1) * 64;
    f32x4 acc[4][4] = {};
    #pragma unroll
    for (int ks = 0; ks < 2; ++ks) {
        bf16x8 af[4], bf[4];
        #pragma unroll
        for (int mt = 0; mt < 4; ++mt)
            af[mt] = *(const bf16x8*)&Gt[(wt0 + mt * 16 + lm) * 72 + ks * 32 + q4 * 8];
        #pragma unroll
        for (int ntt = 0; ntt < 4; ++ntt)
            bf[ntt] = *(const bf16x8*)&ZT[(wn0 + ntt * 16 + lm) * 72 + ks * 32 + q4 * 8];
        #pragma unroll
        for (int mt = 0; mt < 4; ++mt)
            #pragma unroll
            for (int ntt = 0; ntt < 4; ++ntt)
                acc[mt][ntt] = __builtin_amdgcn_mfma_f32_16x16x32_bf16(
                    af[mt], bf[ntt], acc[mt][ntt], 0, 0, 0);
    }
    #pragma unroll
    for (int ntt = 0; ntt < 4; ++ntt) {
        int n = n0 + wn0 + ntt * 16 + lm;
        float bov = bo[n];
        #pragma unroll
        for (int mt = 0; mt < 4; ++mt)
            #pragma unroll
            for (int r = 0; r < 4; ++r) {
                int t = t0 + wt0 + mt * 16 + q4 * 4 + r;
                out[(size_t)(b * 4096 + t) * 1024 + n] = acc[mt][ntt][r] + bov;
            }
    }
}

// ---------------------------------------------------------------------------
extern "C" void kernel_launch(void* const* d_in, const int* in_sizes, int n_in,
                              void* d_out, int out_size, void* d_ws, size_t ws_size,
                              hipStream_t stream) {
    const float* q  = (const float*)d_in[0];
    const float* Wv = (const float*)d_in[1];
    const float* bv = (const float*)d_in[2];
    const float* Wo = (const float*)d_in[3];
    const float* bo = (const float*)d_in[4];
    const float* wr = (const float*)d_in[5];
    const float* wi = (const float*)d_in[6];
    float* out = (float*)d_out;

    char* ws = (char*)d_ws;
    unsigned short* F  = (unsigned short*)(ws);                           // 512 KB
    unsigned short* G  = (unsigned short*)(ws + (512 << 10));             // 512 KB
    float*          A  = (float*)(ws + (1 << 20));                        // 1 MB fp32
    unsigned short* Y  = (unsigned short*)(ws + (2 << 20));               // 512 KB
    unsigned short* Zb = (unsigned short*)(ws + (2 << 20) + (512 << 10)); // 512 KB
    float*          P1 = (float*)(ws + (3u << 20));                       // 8 MB
    float*          P2 = (float*)(ws + (11u << 20));                      // 8 MB

    hipLaunchKernelGGL(k_init,       dim3(1024), dim3(256), 0, stream, F, G, A);
    hipLaunchKernelGGL(k_dft_fwd,    dim3(2048), dim3(64),  0, stream, q, F, A);
    hipLaunchKernelGGL((k_gemm_bt<0>), dim3(256), dim3(256), 0, stream, (const void*)A, Wv, P1);
    hipLaunchKernelGGL(k_cmul,       dim3(512),  dim3(256), 0, stream, P1, bv, wr, wi, Y);
    hipLaunchKernelGGL((k_gemm_bt<1>), dim3(256), dim3(256), 0, stream, (const void*)Y, Wo, P2);
    hipLaunchKernelGGL(k_reduce8,    dim3(1024), dim3(256), 0, stream, P2, Zb);
    hipLaunchKernelGGL(k_dft_inv,    dim3(1024), dim3(256), 0, stream, G, Zb, bo, out);
}